// Round 2
// baseline (606.359 us; speedup 1.0000x reference)
//
#include <hip/hip_runtime.h>

#define N_NODES 100000
#define N_EDGES 3200000
#define F_IN 512
#define F_OUT 256

typedef short bf16x8 __attribute__((ext_vector_type(8)));
typedef float f32x4 __attribute__((ext_vector_type(4)));
typedef unsigned u32x4 __attribute__((ext_vector_type(4)));

__device__ __forceinline__ short f2b(float f) {
    unsigned u = __builtin_bit_cast(unsigned, f);
    u += 0x7fffu + ((u >> 16) & 1u);   // round-to-nearest-even
    return (short)(u >> 16);
}
__device__ __forceinline__ float b2f(short s) {
    unsigned u = ((unsigned)(unsigned short)s) << 16;
    return __builtin_bit_cast(float, u);
}
// pack two fp32 -> two bf16 (round-half-up): 2 adds + 1 v_perm
__device__ __forceinline__ unsigned pack2(float f0, float f1) {
    unsigned u0 = __builtin_bit_cast(unsigned, f0) + 0x8000u;
    unsigned u1 = __builtin_bit_cast(unsigned, f1) + 0x8000u;
    return __builtin_amdgcn_perm(u1, u0, 0x07060302);  // [u0.hi16, u1.hi16]
}
__device__ __forceinline__ void load_lds16(const float* g, void* l) {
    __builtin_amdgcn_global_load_lds(
        (const __attribute__((address_space(1))) unsigned*)g,
        (__attribute__((address_space(3))) unsigned*)l, 16, 0, 0);
}

// --- Kernel 0a: W [512][256] fp32 -> Wt [256][512] bf16 (transposed) ---
__global__ void k_wconv(const float* __restrict__ W, short* __restrict__ Wt) {
    int idx = blockIdx.x * 256 + threadIdx.x;
    int k = idx >> 8;
    int n = idx & 255;
    Wt[n * F_IN + k] = f2b(W[idx]);
}

// --- Kernel 0b: row_ptr via lower_bound on sorted edge_row ---
__global__ void k_rowptr(const int* __restrict__ erow, int* __restrict__ rp) {
    int i = blockIdx.x * 256 + threadIdx.x;
    if (i > N_NODES) return;
    int lo = 0, hi = N_EDGES;
    while (lo < hi) {
        int mid = (lo + hi) >> 1;
        if (erow[mid] < i) lo = mid + 1; else hi = mid;
    }
    rp[i] = lo;
}

// --- Kernel 1: S = x @ W (bf16 MFMA). Block tile 128x256, 8 waves 2x4,
// wave tile 64x64.
// v3: (a) register double-buffer for Wt fragments so the compiler's wait
//     before MFMA is vmcnt(6), never vmcnt(0) -> staging prefetch survives;
// (b) XOR-swizzled A-tile (pre-swizzled global source per rule #21, since
//     global_load_lds dest is linear-only): kills the 16-way bank conflict
//     of the 128B-stride row reads; (c) WAR fence = lgkmcnt(0) + s_barrier.
__global__ __launch_bounds__(512, 4) void k_gemm(const float* __restrict__ X,
                                                 const short* __restrict__ Wt,
                                                 short* __restrict__ S) {
    __shared__ float As[2][128 * 32];   // 2 x 16 KB, row stride 128 B
    const int tid  = threadIdx.x;
    const int wave = tid >> 6;
    const int lane = tid & 63;
    const int wr   = wave >> 2;       // 0..1  row group (64 rows)
    const int wc   = wave & 3;        // 0..3  col group (64 cols)
    const int l15  = lane & 15, quad = lane >> 4;
    const long row_base = (long)blockIdx.x * 128;

    f32x4 acc[4][4];
#pragma unroll
    for (int i = 0; i < 4; ++i)
#pragma unroll
        for (int j = 0; j < 4; ++j) acc[i][j] = (f32x4){0.f, 0.f, 0.f, 0.f};

    // staging: thread t covers LDS row (t>>3), 16B chunk (t&7).
    // source k-chunk is XOR-swizzled by row&7 (involution; read side undoes it)
    const int srow = tid >> 3;
    const int schunk = (tid & 7) ^ (srow & 7);
    long gr0 = row_base + srow;
    long gr1 = gr0 + 64;
    if (gr0 >= N_NODES) gr0 = N_NODES - 1;   // clamp pad rows (discarded later)
    if (gr1 >= N_NODES) gr1 = N_NODES - 1;
    const float* gp0 = X + gr0 * F_IN + schunk * 4;
    const float* gp1 = X + gr1 * F_IN + schunk * 4;
    // wave-uniform LDS bases (HW adds lane*16)
    char* lbase = (char*)As + wave * 1024;

    const short* wtb = Wt + (wc * 64 + l15) * F_IN + quad * 8;
    // swizzled read offsets: chunk c of row r lives at LDS chunk c^(r&7)
    const int sw = l15 & 7;
    const int c0 = ((quad * 2) ^ sw) * 16;       // byte offset of k-chunk quad*2
    const int c1 = ((quad * 2 + 1) ^ sw) * 16;   // byte offset of k-chunk quad*2+1
    const int arow_byte = (wr * 64 + l15) * 128;

    // prologue: Wt frags for k0=0 and stage k0=0 into buffer 0
    bf16x8 bcur[4];
#pragma unroll
    for (int j = 0; j < 4; ++j)
        bcur[j] = *(const bf16x8*)(wtb + j * 16 * F_IN);
    load_lds16(gp0, lbase);
    load_lds16(gp1, lbase + 8192);

#pragma unroll 1
    for (int k0 = 0; k0 < F_IN; k0 += 32) {
        const int cur = (k0 >> 5) & 1;
        bf16x8 bnxt[4];
        if (k0 + 32 < F_IN) {
            // next iter's Wt frags FIRST, then staging -> queue [B(4),S(2)]
#pragma unroll
            for (int j = 0; j < 4; ++j)
                bnxt[j] = *(const bf16x8*)(wtb + j * 16 * F_IN + k0 + 32);
            char* lnext = lbase + (cur ^ 1) * 16384;
            load_lds16(gp0 + k0 + 32, lnext);
            load_lds16(gp1 + k0 + 32, lnext + 8192);
            // retire exactly the previous iteration's 6 ops (B+S); keep 6 in flight
            asm volatile("s_waitcnt vmcnt(6)" ::: "memory");
        } else {
            asm volatile("s_waitcnt vmcnt(0)" ::: "memory");
        }
        __builtin_amdgcn_s_barrier();   // all waves' cur-buffer DMA writes visible

        const char* abase = (const char*)As + cur * 16384 + arow_byte;
#pragma unroll
        for (int i = 0; i < 4; ++i) {
            const char* ap = abase + i * 16 * 128;
            f32x4 x0 = *(const f32x4*)(ap + c0);
            f32x4 x1 = *(const f32x4*)(ap + c1);
            u32x4 pv = { pack2(x0.x, x0.y), pack2(x0.z, x0.w),
                         pack2(x1.x, x1.y), pack2(x1.z, x1.w) };
            bf16x8 afrag = __builtin_bit_cast(bf16x8, pv);
#pragma unroll
            for (int j = 0; j < 4; ++j)
                acc[i][j] = __builtin_amdgcn_mfma_f32_16x16x32_bf16(
                    afrag, bcur[j], acc[i][j], 0, 0, 0);
        }

        // this wave's LDS reads complete before anyone overwrites cur buffer
        asm volatile("s_waitcnt lgkmcnt(0)" ::: "memory");
        __builtin_amdgcn_s_barrier();
        if (k0 + 32 < F_IN) {
#pragma unroll
            for (int j = 0; j < 4; ++j) bcur[j] = bnxt[j];
        }
    }

    // epilogue: C/D layout col=lane&15, row=quad*4+reg
#pragma unroll
    for (int i = 0; i < 4; ++i) {
#pragma unroll
        for (int rg = 0; rg < 4; ++rg) {
            long gm = row_base + wr * 64 + i * 16 + quad * 4 + rg;
            if (gm < N_NODES) {
#pragma unroll
                for (int j = 0; j < 4; ++j) {
                    int gn = wc * 64 + j * 16 + l15;
                    S[gm * F_OUT + gn] = f2b(acc[i][j][rg]);
                }
            }
        }
    }
}

// --- Kernel 2: out = spmm(adj, S). 2 rows per wave (one per half-wave),
// lane owns 8 cols (16B gather).
// v3: cooperative edge loads (32 edges per 2 coalesced VMEM ops) broadcast
// via __shfl, plus group-level software pipeline: prefetch the next 4
// gathers while FMA-ing the current 4 -> up to 8 gathers in flight.
__global__ __launch_bounds__(256) void k_spmm(const short* __restrict__ S,
                                              const int* __restrict__ ecol,
                                              const float* __restrict__ ev,
                                              const int* __restrict__ rp,
                                              float* __restrict__ out) {
    const int wave = threadIdx.x >> 6, lane = threadIdx.x & 63;
    const int half = lane >> 5, hl = lane & 31;
    const int r = (blockIdx.x * 4 + wave) * 2 + half;   // grid 12500 -> r < 100000
    const int lo = rp[r], hi = rp[r + 1];
    const short* sp = S + hl * 8;
    const int lb = half * 32;
    float a[8] = {0.f, 0.f, 0.f, 0.f, 0.f, 0.f, 0.f, 0.f};

#pragma unroll 1
    for (int base = lo; base < hi; base += 32) {
        // cooperative: lane hl owns edge base+hl of this row's chunk
        int eidx = base + hl;
        bool inb = eidx < hi;
        int   cl = inb ? ecol[eidx] : 0;
        float vl = inb ? ev[eidx]   : 0.f;   // pad edges contribute 0
        int n = hi - base; if (n > 32) n = 32;
        int n4 = (n + 3) & ~3;               // pad to x4 (<=3 wasted gathers)

        float vc[4]; bf16x8 ss[4];
#pragma unroll
        for (int u = 0; u < 4; ++u) {
            int c = __shfl(cl, lb + u);
            vc[u] = __shfl(vl, lb + u);
            ss[u] = *(const bf16x8*)(sp + c * 256);
        }
#pragma unroll 1
        for (int j = 4; j < n4; j += 4) {
            float nv[4]; bf16x8 ns[4];
#pragma unroll
            for (int u = 0; u < 4; ++u) {        // issue next group's gathers
                int c = __shfl(cl, lb + j + u);
                nv[u] = __shfl(vl, lb + j + u);
                ns[u] = *(const bf16x8*)(sp + c * 256);
            }
#pragma unroll
            for (int u = 0; u < 4; ++u)          // consume current group
#pragma unroll
                for (int i = 0; i < 8; ++i)
                    a[i] += vc[u] * b2f(ss[u][i]);
#pragma unroll
            for (int u = 0; u < 4; ++u) { vc[u] = nv[u]; ss[u] = ns[u]; }
        }
#pragma unroll
        for (int u = 0; u < 4; ++u)              // tail group
#pragma unroll
            for (int i = 0; i < 8; ++i)
                a[i] += vc[u] * b2f(ss[u][i]);
    }
    f32x4 o0 = {a[0], a[1], a[2], a[3]};
    f32x4 o1 = {a[4], a[5], a[6], a[7]};
    float* op = out + (long)r * F_OUT + hl * 8;
    *(f32x4*)op = o0;
    *(f32x4*)(op + 4) = o1;
}

extern "C" void kernel_launch(void* const* d_in, const int* in_sizes, int n_in,
                              void* d_out, int out_size, void* d_ws, size_t ws_size,
                              hipStream_t stream) {
    const float* x    = (const float*)d_in[0];
    const float* w    = (const float*)d_in[1];
    const int*   erow = (const int*)d_in[2];
    const int*   ecol = (const int*)d_in[3];
    const float* ev   = (const float*)d_in[4];
    float* out = (float*)d_out;

    // ws layout: [0,262144) Wt bf16 | [262144,662148) row_ptr | [1MiB,+51.2MB) S bf16
    char* ws = (char*)d_ws;
    short* Wt = (short*)ws;
    int*   rp = (int*)(ws + 262144);
    short* S  = (short*)(ws + (1 << 20));

    k_wconv<<<512, 256, 0, stream>>>(w, Wt);
    k_rowptr<<<(N_NODES + 256) / 256, 256, 0, stream>>>(erow, rp);
    k_gemm<<<(N_NODES + 127) / 128, 512, 0, stream>>>(x, Wt, S);
    k_spmm<<<N_NODES / 8, 256, 0, stream>>>(S, ecol, ev, rp, out);
}

// Round 3
// 579.068 us; speedup vs baseline: 1.0471x; 1.0471x over previous
//
#include <hip/hip_runtime.h>

#define N_NODES 100000
#define N_EDGES 3200000
#define F_IN 512
#define F_OUT 256

typedef short bf16x8 __attribute__((ext_vector_type(8)));
typedef short bf16x4 __attribute__((ext_vector_type(4)));
typedef float f32x4 __attribute__((ext_vector_type(4)));
typedef unsigned u32x4 __attribute__((ext_vector_type(4)));

__device__ __forceinline__ short f2b(float f) {
    unsigned u = __builtin_bit_cast(unsigned, f);
    u += 0x7fffu + ((u >> 16) & 1u);   // round-to-nearest-even
    return (short)(u >> 16);
}
__device__ __forceinline__ float b2f(short s) {
    unsigned u = ((unsigned)(unsigned short)s) << 16;
    return __builtin_bit_cast(float, u);
}
// pack two fp32 -> two bf16 (round-half-up): 2 adds + 1 v_perm
__device__ __forceinline__ unsigned pack2(float f0, float f1) {
    unsigned u0 = __builtin_bit_cast(unsigned, f0) + 0x8000u;
    unsigned u1 = __builtin_bit_cast(unsigned, f1) + 0x8000u;
    return __builtin_amdgcn_perm(u1, u0, 0x07060302);  // [u0.hi16, u1.hi16]
}
__device__ __forceinline__ void load_lds16(const void* g, void* l) {
    __builtin_amdgcn_global_load_lds(
        (const __attribute__((address_space(1))) unsigned*)g,
        (__attribute__((address_space(3))) unsigned*)l, 16, 0, 0);
}

// --- Kernel 0a: W [512][256] fp32 -> Wt [256][512] bf16 (transposed) ---
__global__ void k_wconv(const float* __restrict__ W, short* __restrict__ Wt) {
    int idx = blockIdx.x * 256 + threadIdx.x;
    int k = idx >> 8;
    int n = idx & 255;
    Wt[n * F_IN + k] = f2b(W[idx]);
}

// --- Kernel 0b: row_ptr via lower_bound on sorted edge_row ---
__global__ void k_rowptr(const int* __restrict__ erow, int* __restrict__ rp) {
    int i = blockIdx.x * 256 + threadIdx.x;
    if (i > N_NODES) return;
    int lo = 0, hi = N_EDGES;
    while (lo < hi) {
        int mid = (lo + hi) >> 1;
        if (erow[mid] < i) lo = mid + 1; else hi = mid;
    }
    rp[i] = lo;
}

// --- Kernel 1: S = x @ W (bf16 MFMA). Block tile 128x256, 8 waves 2x4,
// wave tile 64x64, K-step 32, 16 steps.
// v4: BOTH A and B staged in LDS via global_load_lds (double-buffered,
// 64 KB total -> 2 blocks/CU). No register B-buffer -> VGPR ~105, no spill
// under __launch_bounds__(512,4). Counted vmcnt(4) keeps next step's 16 KB
// in flight across the barrier. XOR-swizzled LDS via pre-swizzled global
// sources (A: chunk^=(row&7), B: chunk^=(n&3)) -> <=2-way bank conflicts.
__global__ __launch_bounds__(512, 4) void k_gemm(const float* __restrict__ X,
                                                 const short* __restrict__ Wt,
                                                 short* __restrict__ S) {
    __shared__ char lds[65536];               // A: [0,32K) 2 bufs; B: [32K,64K)
    char* ldsA = lds;
    char* ldsB = lds + 32768;
    const int tid  = threadIdx.x;
    const int wave = tid >> 6;
    const int lane = tid & 63;
    const int wr   = wave >> 2;       // 0..1  row group (64 rows)
    const int wc   = wave & 3;        // 0..3  col group (64 cols)
    const int l15  = lane & 15, quad = lane >> 4;
    const long row_base = (long)blockIdx.x * 128;

    f32x4 acc[4][4];
#pragma unroll
    for (int i = 0; i < 4; ++i)
#pragma unroll
        for (int j = 0; j < 4; ++j) acc[i][j] = (f32x4){0.f, 0.f, 0.f, 0.f};

    // ---- A staging: thread t covers LDS row (t>>3) [+64], chunk (t&7).
    // source k-chunk pre-swizzled by row&7 (read side undoes it)
    const int srow = tid >> 3;
    const int schunk = (tid & 7) ^ (srow & 7);
    long gr0 = row_base + srow;
    long gr1 = gr0 + 64;
    if (gr0 >= N_NODES) gr0 = N_NODES - 1;   // clamp pad rows (discarded later)
    if (gr1 >= N_NODES) gr1 = N_NODES - 1;
    const float* gp0 = X + gr0 * F_IN + schunk * 4;
    const float* gp1 = X + gr1 * F_IN + schunk * 4;

    // ---- B staging: wave w, issue q covers linear 16B-chunks [w*128+q*64, +64)
    // chunk idx -> n = idx>>2, store-chunk = idx&3; source chunk = sc ^ (n&3)
    const int bidx0 = wave * 128 + lane;
    const int bn0 = bidx0 >> 2, bs0 = bidx0 & 3;
    const int bidx1 = bidx0 + 64;
    const int bn1 = bidx1 >> 2, bs1 = bidx1 & 3;
    const short* bsrc0 = Wt + bn0 * F_IN + (bs0 ^ (bn0 & 3)) * 8;
    const short* bsrc1 = Wt + bn1 * F_IN + (bs1 ^ (bn1 & 3)) * 8;

    // ---- LDS read offsets (swizzled)
    const int sw = l15 & 7;
    const int c0 = ((quad * 2) ^ sw) * 16;        // A k-chunk quad*2
    const int c1 = ((quad * 2 + 1) ^ sw) * 16;    // A k-chunk quad*2+1
    const int arow_byte = (wr * 64 + l15) * 128;
    const int bchunk = (quad ^ (l15 & 3)) * 16;   // B k-chunk quad
    const int brow_byte = (wc * 64 + l15) * 64;

    // prologue: stage step 0 into buffer 0 (A 2 ops + B 2 ops per thread)
    {
        char* a0 = ldsA + wave * 1024;
        load_lds16(gp0, a0);
        load_lds16(gp1, a0 + 8192);
        char* b0 = ldsB + wave * 2048;
        load_lds16(bsrc0, b0);
        load_lds16(bsrc1, b0 + 1024);
    }

#pragma unroll 1
    for (int k0 = 0; k0 < F_IN; k0 += 32) {
        const int cur = (k0 >> 5) & 1;
        if (k0 + 32 < F_IN) {
            const int kk = k0 + 32;
            char* a0 = ldsA + (cur ^ 1) * 16384 + wave * 1024;
            load_lds16(gp0 + kk, a0);
            load_lds16(gp1 + kk, a0 + 8192);
            char* b0 = ldsB + (cur ^ 1) * 16384 + wave * 2048;
            load_lds16(bsrc0 + kk, b0);
            load_lds16(bsrc1 + kk, b0 + 1024);
            // retire exactly the previous step's 4 DMA ops; keep 4 in flight
            asm volatile("s_waitcnt vmcnt(4)" ::: "memory");
        } else {
            asm volatile("s_waitcnt vmcnt(0)" ::: "memory");
        }
        __builtin_amdgcn_s_barrier();   // cur-buffer DMA visible to all waves

        const char* abase = ldsA + cur * 16384 + arow_byte;
        const char* bbase = ldsB + cur * 16384 + brow_byte;
        bf16x8 bfrag[4];
#pragma unroll
        for (int j = 0; j < 4; ++j)
            bfrag[j] = *(const bf16x8*)(bbase + j * 1024 + bchunk);
#pragma unroll
        for (int i = 0; i < 4; ++i) {
            const char* ap = abase + i * 16 * 128;
            f32x4 x0 = *(const f32x4*)(ap + c0);
            f32x4 x1 = *(const f32x4*)(ap + c1);
            u32x4 pv = { pack2(x0.x, x0.y), pack2(x0.z, x0.w),
                         pack2(x1.x, x1.y), pack2(x1.z, x1.w) };
            bf16x8 afrag = __builtin_bit_cast(bf16x8, pv);
#pragma unroll
            for (int j = 0; j < 4; ++j)
                acc[i][j] = __builtin_amdgcn_mfma_f32_16x16x32_bf16(
                    afrag, bfrag[j], acc[i][j], 0, 0, 0);
        }

        // this wave's LDS reads complete before anyone overwrites cur buffer
        asm volatile("s_waitcnt lgkmcnt(0)" ::: "memory");
        __builtin_amdgcn_s_barrier();
    }

    // epilogue: C/D layout col=lane&15, row=quad*4+reg
#pragma unroll
    for (int i = 0; i < 4; ++i) {
#pragma unroll
        for (int rg = 0; rg < 4; ++rg) {
            long gm = row_base + wr * 64 + i * 16 + quad * 4 + rg;
            if (gm < N_NODES) {
#pragma unroll
                for (int j = 0; j < 4; ++j) {
                    int gn = wc * 64 + j * 16 + l15;
                    S[gm * F_OUT + gn] = f2b(acc[i][j][rg]);
                }
            }
        }
    }
}

// --- Kernel 2: out = spmm(adj, S).
// v4: ONE ROW PER WAVE. Row id is wave-uniform -> edge index/value loads
// are uniform (readfirstlane belt-and-suspenders) and should select to
// scalar s_load on the SMEM pipe; gather address = SGPR row base + lane*8.
// Lane owns 4 cols (8B bf16x4 gather; wave still moves 512B per inst).
// 8 independent gathers in flight per wave; no shfl, ~6 VALU/edge.
__global__ __launch_bounds__(256) void k_spmm(const short* __restrict__ S,
                                              const int* __restrict__ ecol,
                                              const float* __restrict__ ev,
                                              const int* __restrict__ rp,
                                              float* __restrict__ out) {
    const int wid  = __builtin_amdgcn_readfirstlane((int)(threadIdx.x >> 6));
    const int lane = threadIdx.x & 63;
    const int r = blockIdx.x * 4 + wid;          // grid 25000 -> r < 100000
    const int lo = __builtin_amdgcn_readfirstlane(rp[r]);
    const int hi = __builtin_amdgcn_readfirstlane(rp[r + 1]);
    const short* sp = S + lane * 4;
    float a0 = 0.f, a1 = 0.f, a2 = 0.f, a3 = 0.f;

#pragma unroll 1
    for (int base = lo; base < hi; base += 8) {
        int cc[8]; float vv[8];
#pragma unroll
        for (int u = 0; u < 8; ++u) {
            int e = base + u;
            int ee = e < hi ? e : hi - 1;        // uniform, branchless pad
            cc[u] = __builtin_amdgcn_readfirstlane(ecol[ee]);
            int vb = __builtin_bit_cast(int, e < hi ? ev[ee] : 0.f);
            vv[u] = __builtin_bit_cast(float, __builtin_amdgcn_readfirstlane(vb));
        }
        bf16x4 g[8];
#pragma unroll
        for (int u = 0; u < 8; ++u)              // 8 gathers back-to-back
            g[u] = *(const bf16x4*)(sp + cc[u] * 256);
#pragma unroll
        for (int u = 0; u < 8; ++u) {
            a0 += vv[u] * b2f(g[u][0]);
            a1 += vv[u] * b2f(g[u][1]);
            a2 += vv[u] * b2f(g[u][2]);
            a3 += vv[u] * b2f(g[u][3]);
        }
    }
    f32x4 o = {a0, a1, a2, a3};
    *(f32x4*)(out + (long)r * F_OUT + lane * 4) = o;
}

extern "C" void kernel_launch(void* const* d_in, const int* in_sizes, int n_in,
                              void* d_out, int out_size, void* d_ws, size_t ws_size,
                              hipStream_t stream) {
    const float* x    = (const float*)d_in[0];
    const float* w    = (const float*)d_in[1];
    const int*   erow = (const int*)d_in[2];
    const int*   ecol = (const int*)d_in[3];
    const float* ev   = (const float*)d_in[4];
    float* out = (float*)d_out;

    // ws layout: [0,262144) Wt bf16 | [262144,662148) row_ptr | [1MiB,+51.2MB) S bf16
    char* ws = (char*)d_ws;
    short* Wt = (short*)ws;
    int*   rp = (int*)(ws + 262144);
    short* S  = (short*)(ws + (1 << 20));

    k_wconv<<<512, 256, 0, stream>>>(w, Wt);
    k_rowptr<<<(N_NODES + 256) / 256, 256, 0, stream>>>(erow, rp);
    k_gemm<<<(N_NODES + 127) / 128, 512, 0, stream>>>(x, Wt, S);
    k_spmm<<<N_NODES / 4, 256, 0, stream>>>(S, ecol, ev, rp, out);
}

// Round 5
// 576.944 us; speedup vs baseline: 1.0510x; 1.0037x over previous
//
#include <hip/hip_runtime.h>

#define N_NODES 100000
#define N_EDGES 3200000
#define F_IN 512
#define F_OUT 256

typedef short bf16x8 __attribute__((ext_vector_type(8)));
typedef short bf16x4 __attribute__((ext_vector_type(4)));
typedef float f32x4 __attribute__((ext_vector_type(4)));
typedef unsigned u32x4 __attribute__((ext_vector_type(4)));

__device__ __forceinline__ short f2b(float f) {
    unsigned u = __builtin_bit_cast(unsigned, f);
    u += 0x7fffu + ((u >> 16) & 1u);   // round-to-nearest-even
    return (short)(u >> 16);
}
__device__ __forceinline__ float b2f(short s) {
    unsigned u = ((unsigned)(unsigned short)s) << 16;
    return __builtin_bit_cast(float, u);
}
// pack two fp32 -> two bf16 (round-half-up): 2 adds + 1 v_perm
__device__ __forceinline__ unsigned pack2(float f0, float f1) {
    unsigned u0 = __builtin_bit_cast(unsigned, f0) + 0x8000u;
    unsigned u1 = __builtin_bit_cast(unsigned, f1) + 0x8000u;
    return __builtin_amdgcn_perm(u1, u0, 0x07060302);  // [u0.hi16, u1.hi16]
}
__device__ __forceinline__ void load_lds16(const void* g, void* l) {
    __builtin_amdgcn_global_load_lds(
        (const __attribute__((address_space(1))) unsigned*)g,
        (__attribute__((address_space(3))) unsigned*)l, 16, 0, 0);
}

// --- Kernel 0: fused prep. blocks [0,512): W [512][256] fp32 -> Wt [256][512]
// bf16 transposed. blocks [512,904): row_ptr via lower_bound on sorted erow.
__global__ void k_prep(const float* __restrict__ W, short* __restrict__ Wt,
                       const int* __restrict__ erow, int* __restrict__ rp) {
    int b = blockIdx.x;
    if (b < 512) {
        int idx = b * 256 + threadIdx.x;
        int k = idx >> 8;
        int n = idx & 255;
        Wt[n * F_IN + k] = f2b(W[idx]);
    } else {
        int i = (b - 512) * 256 + threadIdx.x;
        if (i > N_NODES) return;
        int lo = 0, hi = N_EDGES;
        while (lo < hi) {
            int mid = (lo + hi) >> 1;
            if (erow[mid] < i) lo = mid + 1; else hi = mid;
        }
        rp[i] = lo;
    }
}

// --- Kernel 1: S = x @ W (bf16 MFMA). Block tile 128x256, 8 waves 2x4,
// wave tile 64x64, K-step 32, 16 steps.
// v5: as v4 (A+B LDS double-buffered via global_load_lds, counted vmcnt(4),
// pre-swizzled global sources per rule #21) with the B-swizzle corrected:
// (n&3) -> ((n>>1)&3). The old term left bank-quad = 4*(l15&1)+(quad^(l15&3))
// = only 4 distinct values over 16 lanes -> 4-way conflict on every B
// ds_read_b128. New term spreads lanes over all 8 bank-quads -> 2-way (free).
__global__ __launch_bounds__(512, 4) void k_gemm(const float* __restrict__ X,
                                                 const short* __restrict__ Wt,
                                                 short* __restrict__ S) {
    __shared__ char lds[65536];               // A: [0,32K) 2 bufs; B: [32K,64K)
    char* ldsA = lds;
    char* ldsB = lds + 32768;
    const int tid  = threadIdx.x;
    const int wave = tid >> 6;
    const int lane = tid & 63;
    const int wr   = wave >> 2;       // 0..1  row group (64 rows)
    const int wc   = wave & 3;        // 0..3  col group (64 cols)
    const int l15  = lane & 15, quad = lane >> 4;
    const long row_base = (long)blockIdx.x * 128;

    f32x4 acc[4][4];
#pragma unroll
    for (int i = 0; i < 4; ++i)
#pragma unroll
        for (int j = 0; j < 4; ++j) acc[i][j] = (f32x4){0.f, 0.f, 0.f, 0.f};

    // ---- A staging: thread t covers LDS row (t>>3) [+64], chunk (t&7).
    // source k-chunk pre-swizzled by row&7 (read side undoes it)
    const int srow = tid >> 3;
    const int schunk = (tid & 7) ^ (srow & 7);
    long gr0 = row_base + srow;
    long gr1 = gr0 + 64;
    if (gr0 >= N_NODES) gr0 = N_NODES - 1;   // clamp pad rows (discarded later)
    if (gr1 >= N_NODES) gr1 = N_NODES - 1;
    const float* gp0 = X + gr0 * F_IN + schunk * 4;
    const float* gp1 = X + gr1 * F_IN + schunk * 4;

    // ---- B staging: wave w, issue q covers linear 16B-chunks [w*128+q*64, +64)
    // chunk idx -> n = idx>>2, store-chunk = idx&3; source chunk = sc ^ ((n>>1)&3)
    const int bidx0 = wave * 128 + lane;
    const int bn0 = bidx0 >> 2, bs0 = bidx0 & 3;
    const int bidx1 = bidx0 + 64;
    const int bn1 = bidx1 >> 2, bs1 = bidx1 & 3;
    const short* bsrc0 = Wt + bn0 * F_IN + (bs0 ^ ((bn0 >> 1) & 3)) * 8;
    const short* bsrc1 = Wt + bn1 * F_IN + (bs1 ^ ((bn1 >> 1) & 3)) * 8;

    // ---- LDS read offsets (swizzled)
    const int sw = l15 & 7;
    const int c0 = ((quad * 2) ^ sw) * 16;        // A k-chunk quad*2
    const int c1 = ((quad * 2 + 1) ^ sw) * 16;    // A k-chunk quad*2+1
    const int arow_byte = (wr * 64 + l15) * 128;
    const int bchunk = (quad ^ ((l15 >> 1) & 3)) * 16;   // B k-chunk quad
    const int brow_byte = (wc * 64 + l15) * 64;

    // prologue: stage step 0 into buffer 0 (A 2 ops + B 2 ops per thread)
    {
        char* a0 = ldsA + wave * 1024;
        load_lds16(gp0, a0);
        load_lds16(gp1, a0 + 8192);
        char* b0 = ldsB + wave * 2048;
        load_lds16(bsrc0, b0);
        load_lds16(bsrc1, b0 + 1024);
    }

#pragma unroll 1
    for (int k0 = 0; k0 < F_IN; k0 += 32) {
        const int cur = (k0 >> 5) & 1;
        if (k0 + 32 < F_IN) {
            const int kk = k0 + 32;
            char* a0 = ldsA + (cur ^ 1) * 16384 + wave * 1024;
            load_lds16(gp0 + kk, a0);
            load_lds16(gp1 + kk, a0 + 8192);
            char* b0 = ldsB + (cur ^ 1) * 16384 + wave * 2048;
            load_lds16(bsrc0 + kk, b0);
            load_lds16(bsrc1 + kk, b0 + 1024);
            // retire exactly the previous step's 4 DMA ops; keep 4 in flight
            asm volatile("s_waitcnt vmcnt(4)" ::: "memory");
        } else {
            asm volatile("s_waitcnt vmcnt(0)" ::: "memory");
        }
        __builtin_amdgcn_s_barrier();   // cur-buffer DMA visible to all waves

        const char* abase = ldsA + cur * 16384 + arow_byte;
        const char* bbase = ldsB + cur * 16384 + brow_byte;
        bf16x8 bfrag[4];
#pragma unroll
        for (int j = 0; j < 4; ++j)
            bfrag[j] = *(const bf16x8*)(bbase + j * 1024 + bchunk);
#pragma unroll
        for (int i = 0; i < 4; ++i) {
            const char* ap = abase + i * 16 * 128;
            f32x4 x0 = *(const f32x4*)(ap + c0);
            f32x4 x1 = *(const f32x4*)(ap + c1);
            u32x4 pv = { pack2(x0.x, x0.y), pack2(x0.z, x0.w),
                         pack2(x1.x, x1.y), pack2(x1.z, x1.w) };
            bf16x8 afrag = __builtin_bit_cast(bf16x8, pv);
#pragma unroll
            for (int j = 0; j < 4; ++j)
                acc[i][j] = __builtin_amdgcn_mfma_f32_16x16x32_bf16(
                    afrag, bfrag[j], acc[i][j], 0, 0, 0);
        }

        // this wave's LDS reads complete before anyone overwrites cur buffer
        asm volatile("s_waitcnt lgkmcnt(0)" ::: "memory");
        __builtin_amdgcn_s_barrier();
    }

    // epilogue: C/D layout col=lane&15, row=quad*4+reg
#pragma unroll
    for (int i = 0; i < 4; ++i) {
#pragma unroll
        for (int rg = 0; rg < 4; ++rg) {
            long gm = row_base + wr * 64 + i * 16 + quad * 4 + rg;
            if (gm < N_NODES) {
#pragma unroll
                for (int j = 0; j < 4; ++j) {
                    int gn = wc * 64 + j * 16 + l15;
                    S[gm * F_OUT + gn] = f2b(acc[i][j][rg]);
                }
            }
        }
    }
}

// --- Kernel 2: out = spmm(adj, S). ONE ROW PER WAVE; edge (c,v) loads are
// wave-uniform (scalarized via readfirstlane); lane owns 4 cols (8B gather,
// wave moves the full contiguous 512B row per instruction).
// v5: software-pipeline the (c,v) loads one 8-edge group ahead -- the next
// group's scalar loads issue in the shadow of the current group's gathers
// instead of serially after the FMAs.
__global__ __launch_bounds__(256) void k_spmm(const short* __restrict__ S,
                                              const int* __restrict__ ecol,
                                              const float* __restrict__ ev,
                                              const int* __restrict__ rp,
                                              float* __restrict__ out) {
    const int wid  = __builtin_amdgcn_readfirstlane((int)(threadIdx.x >> 6));
    const int lane = threadIdx.x & 63;
    const int r = blockIdx.x * 4 + wid;          // grid 25000 -> r < 100000
    const int lo = __builtin_amdgcn_readfirstlane(rp[r]);
    const int hi = __builtin_amdgcn_readfirstlane(rp[r + 1]);
    const short* sp = S + lane * 4;
    float a0 = 0.f, a1 = 0.f, a2 = 0.f, a3 = 0.f;

    int cc[8]; float vv[8];
    if (lo < hi) {
#pragma unroll
        for (int u = 0; u < 8; ++u) {
            int e = lo + u;
            int ee = e < hi ? e : hi - 1;        // uniform, branchless pad
            cc[u] = __builtin_amdgcn_readfirstlane(ecol[ee]);
            int vb = __builtin_bit_cast(int, e < hi ? ev[ee] : 0.f);
            vv[u] = __builtin_bit_cast(float, __builtin_amdgcn_readfirstlane(vb));
        }
    }
#pragma unroll 1
    for (int base = lo; base < hi; base += 8) {
        bf16x4 g[8];
#pragma unroll
        for (int u = 0; u < 8; ++u)              // 8 gathers back-to-back
            g[u] = *(const bf16x4*)(sp + cc[u] * 256);
        int nb = base + 8;
        int nc[8]; float nv[8];
        if (nb < hi) {                           // prefetch next group's (c,v)
#pragma unroll
            for (int u = 0; u < 8; ++u) {
                int e = nb + u;
                int ee = e < hi ? e : hi - 1;
                nc[u] = __builtin_amdgcn_readfirstlane(ecol[ee]);
                int vb = __builtin_bit_cast(int, e < hi ? ev[ee] : 0.f);
                nv[u] = __builtin_bit_cast(float, __builtin_amdgcn_readfirstlane(vb));
            }
        }
#pragma unroll
        for (int u = 0; u < 8; ++u) {
            float v = vv[u];
            a0 += v * b2f(g[u][0]);
            a1 += v * b2f(g[u][1]);
            a2 += v * b2f(g[u][2]);
            a3 += v * b2f(g[u][3]);
        }
#pragma unroll
        for (int u = 0; u < 8; ++u) { cc[u] = nc[u]; vv[u] = nv[u]; }
    }
    f32x4 o = {a0, a1, a2, a3};
    *(f32x4*)(out + (long)r * F_OUT + lane * 4) = o;
}

extern "C" void kernel_launch(void* const* d_in, const int* in_sizes, int n_in,
                              void* d_out, int out_size, void* d_ws, size_t ws_size,
                              hipStream_t stream) {
    const float* x    = (const float*)d_in[0];
    const float* w    = (const float*)d_in[1];
    const int*   erow = (const int*)d_in[2];
    const int*   ecol = (const int*)d_in[3];
    const float* ev   = (const float*)d_in[4];
    float* out = (float*)d_out;

    // ws layout: [0,262144) Wt bf16 | [262144,662148) row_ptr | [1MiB,+51.2MB) S bf16
    char* ws = (char*)d_ws;
    short* Wt = (short*)ws;
    int*   rp = (int*)(ws + 262144);
    short* S  = (short*)(ws + (1 << 20));

    k_prep<<<512 + (N_NODES + 256) / 256, 256, 0, stream>>>(w, Wt, erow, rp);
    k_gemm<<<(N_NODES + 127) / 128, 512, 0, stream>>>(x, Wt, S);
    k_spmm<<<N_NODES / 4, 256, 0, stream>>>(S, ecol, ev, rp, out);
}